// Round 6
// baseline (337.538 us; speedup 1.0000x reference)
//
#include <hip/hip_runtime.h>
#include <hip/hip_bf16.h>

// GCN decoder, 7 dispatches, wave-parallel barrier-free aggregates.
//  prep_t0_k : blocks 0-255: msg0 = lat@W0+b0 -> msgP (frag-major); blocks 256+: W transposes.
//  agg_part_k<L1> : per-wave 32node x 128feat tile, K-split 4 (K=512/wave), grid 2048x64thr.
//      L1=1: A from adj fp32 (frag loads) + writes frag-major bf16 adjP. L1=0: A from adjP (dense).
//      B from msgP: every frag load is one dense 1KB dwordx4. NO LDS, NO barriers ->
//      8 independent waves/CU hide latency (rounds 2-5 were phase-locked at 2 blocks/CU).
//  combine_k<MODE> : sum 4 K-split partials + relu; MODE0: transform -> msgP; MODE1: out-proj*mask.
// Layouts: msgP[b][k>>3][feat][k&7] ; adjP[b][m>>5][k>>3][m&31][k&7].

typedef __bf16 bf16;
typedef __bf16 bf16x4 __attribute__((ext_vector_type(4)));
typedef __bf16 bf16x8 __attribute__((ext_vector_type(8)));
typedef float  f32x16 __attribute__((ext_vector_type(16)));
typedef float  f32x4  __attribute__((ext_vector_type(4)));

static __device__ inline f32x16 mfma32(bf16x8 a, bf16x8 b, f32x16 c) {
    return __builtin_amdgcn_mfma_f32_32x32x16_bf16(a, b, c, 0, 0, 0);
}

#define NB   8
#define NN   2048
#define LAT  64
#define HID  128
#define ODIM 64
#define MSGP_B 262144        // elems per batch in msgP (256 kblk * 128 feat * 8)
#define ADJP_B 4194304       // elems per batch in adjP
#define PART_S 2097152       // floats per K-split slice (8*2048*128)

// ---------------- dispatch 1: transform0 (blocks 0-255) + weight prep (blocks 256+) ----
__global__ __launch_bounds__(256) void prep_t0_k(
    const float* __restrict__ lat, const float* __restrict__ W0,
    const float* __restrict__ b0,
    const float* __restrict__ W1, const float* __restrict__ W2,
    const float* __restrict__ Wout,
    bf16* __restrict__ msgP, bf16* __restrict__ WT1,
    bf16* __restrict__ WT2, bf16* __restrict__ WoutT)
{
    __shared__ __align__(16) bf16 WTs[HID * 72];
    __shared__ __align__(16) bf16 Ms[HID * 72];   // [fo][node 64 + pad 8]
    int tid = threadIdx.x;
    int blk = blockIdx.x;

    if (blk >= 256) {
        int i = (blk - 256) * 256 + tid;
        if (i < HID * HID) { int fo = i >> 7, k = i & 127; WT1[i] = (bf16)W1[k * HID + fo]; return; }
        i -= HID * HID;
        if (i < HID * HID) { int fo = i >> 7, k = i & 127; WT2[i] = (bf16)W2[k * HID + fo]; return; }
        i -= HID * HID;
        if (i < ODIM * HID) { int o = i >> 7, k = i & 127; WoutT[i] = (bf16)Wout[k * ODIM + o]; return; }
        return;
    }

    for (int i = tid; i < LAT * HID; i += 256) {
        int k = i >> 7, fo = i & 127;
        WTs[fo * 72 + k] = (bf16)W0[i];
    }
    __syncthreads();

    int l = tid & 63, w = tid >> 6;
    int lm = l & 31, lh = l >> 5;
    int g0 = blk * 64;
    int b  = g0 >> 11, nb0 = g0 & 2047;

    const bf16*  Wrow = &WTs[(w * 32 + lm) * 72 + lh * 8];
    const float* r0   = lat + (size_t)(g0 + lm) * LAT + lh * 8;
    const float* r1   = r0 + (size_t)32 * LAT;

    f32x16 acc0 = {}, acc1 = {};
#pragma unroll
    for (int k0 = 0; k0 < LAT; k0 += 16) {
        bf16x8 a = *(const bf16x8*)(Wrow + k0);
        f32x4 x0 = *(const f32x4*)(r0 + k0), x1 = *(const f32x4*)(r0 + k0 + 4);
        f32x4 y0 = *(const f32x4*)(r1 + k0), y1 = *(const f32x4*)(r1 + k0 + 4);
        bf16x8 v0, v1;
        v0[0]=(bf16)x0[0]; v0[1]=(bf16)x0[1]; v0[2]=(bf16)x0[2]; v0[3]=(bf16)x0[3];
        v0[4]=(bf16)x1[0]; v0[5]=(bf16)x1[1]; v0[6]=(bf16)x1[2]; v0[7]=(bf16)x1[3];
        v1[0]=(bf16)y0[0]; v1[1]=(bf16)y0[1]; v1[2]=(bf16)y0[2]; v1[3]=(bf16)y0[3];
        v1[4]=(bf16)y1[0]; v1[5]=(bf16)y1[1]; v1[6]=(bf16)y1[2]; v1[7]=(bf16)y1[3];
        acc0 = mfma32(a, v0, acc0);
        acc1 = mfma32(a, v1, acc1);
    }

#pragma unroll
    for (int r = 0; r < 16; ++r) {
        int fo = w * 32 + (r & 3) + 8 * (r >> 2) + 4 * lh;
        float bv = b0[fo];
        Ms[fo * 72 + lm]      = (bf16)(acc0[r] + bv);
        Ms[fo * 72 + 32 + lm] = (bf16)(acc1[r] + bv);
    }
    __syncthreads();

    // packed store: msgP[b][(nb0+n)>>3][fo][n&7]
    {
        int fo = tid & 127, half = tid >> 7;
        bf16* mb = msgP + (size_t)b * MSGP_B;
#pragma unroll
        for (int jj = 0; jj < 4; ++jj) {
            int n0 = half * 32 + jj * 8;
            bf16x8 v = *(const bf16x8*)&Ms[fo * 72 + n0];
            *(bf16x8*)(mb + (size_t)((nb0 + n0) >> 3) * 1024 + fo * 8) = v;
        }
    }
}

// ---------------- aggregates: wave-independent, K-split 4, no LDS/barriers ----------------
template<int L1>
__global__ __launch_bounds__(64) void agg_part_k(
    const float* __restrict__ adjf, const bf16* __restrict__ adjPi,
    bf16* __restrict__ adjPo,
    const bf16* __restrict__ msgP, float* __restrict__ part)
{
    int l = threadIdx.x;
    int lm = l & 31, lh = l >> 5;
    int blk = blockIdx.x;
    int b  = blk & 7;                 // XCD swizzle: batch panel stays L2-local
    int mt = (blk >> 3) & 63;
    int ks = blk >> 9;
    int m0 = mt * 32;
    int kbeg = ks * 512;

    const bf16* Bp = msgP + (size_t)b * MSGP_B + lh * 1024 + lm * 8;  // + k0*128 + c*256

    const float* Af = nullptr; const bf16* Ap = nullptr; bf16* Aw = nullptr;
    if (L1) {
        Af = adjf + (size_t)b * ADJP_B + (size_t)(m0 + lm) * NN + lh * 8;   // + k0
        Aw = adjPo + (size_t)b * ADJP_B + (size_t)mt * 65536 + lh * 256 + lm * 8; // + k0*32
    } else {
        Ap = adjPi + (size_t)b * ADJP_B + (size_t)mt * 65536 + lh * 256 + lm * 8; // + k0*32
    }

    f32x16 acc[4] = {};

#pragma unroll 4
    for (int k0 = kbeg; k0 < kbeg + 512; k0 += 16) {
        bf16x8 av;
        if (L1) {
            f32x4 x0 = *(const f32x4*)(Af + k0);
            f32x4 x1 = *(const f32x4*)(Af + k0 + 4);
            av[0]=(bf16)x0[0]; av[1]=(bf16)x0[1]; av[2]=(bf16)x0[2]; av[3]=(bf16)x0[3];
            av[4]=(bf16)x1[0]; av[5]=(bf16)x1[1]; av[6]=(bf16)x1[2]; av[7]=(bf16)x1[3];
            *(bf16x8*)(Aw + (size_t)k0 * 32) = av;      // frag-major adj writeback
        } else {
            av = *(const bf16x8*)(Ap + (size_t)k0 * 32); // dense 1KB wave load
        }
        const bf16* bp = Bp + (size_t)k0 * 128;
#pragma unroll
        for (int c = 0; c < 4; ++c)
            acc[c] = mfma32(av, *(const bf16x8*)(bp + c * 256), acc[c]);
    }

    float* pp = part + (size_t)ks * PART_S + ((size_t)b * NN + m0) * HID;
#pragma unroll
    for (int r = 0; r < 16; ++r) {
        int row = (r & 3) + 8 * (r >> 2) + 4 * lh;
#pragma unroll
        for (int c = 0; c < 4; ++c)
            pp[row * HID + c * 32 + lm] = acc[c][r];
    }
}

// ---------------- combine: sum K-split partials + relu, then transform / output proj ----
template<int MODE>
__global__ __launch_bounds__(256) void combine_k(
    const float* __restrict__ part, const bf16* __restrict__ WTn,
    const float* __restrict__ biasn, bf16* __restrict__ msgPo,
    const float* __restrict__ mask, float* __restrict__ out)
{
    __shared__ __align__(16) bf16 Hs[64 * 136];   // [node][feat]
    __shared__ __align__(16) bf16 Ms[HID * 72];   // MODE0: [fo][node]
    int tid = threadIdx.x;
    int g0 = blockIdx.x * 64;
    int b  = g0 >> 11, nb0 = g0 & 2047;

    // sum 4 partials + relu -> Hs
    {
        int nl = tid >> 2, f0 = (tid & 3) * 32;
        const float* p = part + (size_t)(g0 + nl) * HID + f0;
#pragma unroll
        for (int j = 0; j < 8; ++j) {
            f32x4 s = *(const f32x4*)(p + j * 4);
            s += *(const f32x4*)(p + PART_S + j * 4);
            s += *(const f32x4*)(p + 2 * PART_S + j * 4);
            s += *(const f32x4*)(p + 3 * PART_S + j * 4);
            bf16x4 v;
            v[0] = (bf16)(s[0] > 0.f ? s[0] : 0.f);
            v[1] = (bf16)(s[1] > 0.f ? s[1] : 0.f);
            v[2] = (bf16)(s[2] > 0.f ? s[2] : 0.f);
            v[3] = (bf16)(s[3] > 0.f ? s[3] : 0.f);
            *(bf16x4*)&Hs[nl * 136 + f0 + j * 4] = v;
        }
    }
    __syncthreads();

    int l = tid & 63, w = tid >> 6;
    int lm = l & 31, lh = l >> 5;

    if (MODE == 0) {
        // C[fo][node] = WTn[fo][:] . h[node][:] ; 64 nodes = 2 accum groups
        const bf16* Arow = WTn + (size_t)(w * 32 + lm) * HID + lh * 8;
        const bf16* B0   = &Hs[lm * 136 + lh * 8];
        const bf16* B1   = &Hs[(32 + lm) * 136 + lh * 8];
        f32x16 a0 = {}, a1 = {};
#pragma unroll
        for (int k0 = 0; k0 < HID; k0 += 16) {
            bf16x8 a = *(const bf16x8*)(Arow + k0);
            a0 = mfma32(a, *(const bf16x8*)(B0 + k0), a0);
            a1 = mfma32(a, *(const bf16x8*)(B1 + k0), a1);
        }
#pragma unroll
        for (int r = 0; r < 16; ++r) {
            int fo = w * 32 + (r & 3) + 8 * (r >> 2) + 4 * lh;
            float bv = biasn[fo];
            Ms[fo * 72 + lm]      = (bf16)(a0[r] + bv);
            Ms[fo * 72 + 32 + lm] = (bf16)(a1[r] + bv);
        }
        __syncthreads();
        int fo = tid & 127, half = tid >> 7;
        bf16* mb = msgPo + (size_t)b * MSGP_B;
#pragma unroll
        for (int jj = 0; jj < 4; ++jj) {
            int n0 = half * 32 + jj * 8;
            bf16x8 v = *(const bf16x8*)&Ms[fo * 72 + n0];
            *(bf16x8*)(mb + (size_t)((nb0 + n0) >> 3) * 1024 + fo * 8) = v;
        }
    } else {
        // C[node][o] = h[node][:] . WoutT[o][:] ; wave w: node group w>>1, o-tile w&1
        int nw = w >> 1, ow = w & 1;
        const bf16* Arow = &Hs[(nw * 32 + lm) * 136 + lh * 8];
        const bf16* Brow = WTn + (size_t)(ow * 32 + lm) * HID + lh * 8;
        f32x16 a2 = {};
#pragma unroll
        for (int k0 = 0; k0 < HID; k0 += 16)
            a2 = mfma32(*(const bf16x8*)(Arow + k0), *(const bf16x8*)(Brow + k0), a2);
        float bv = biasn[ow * 32 + lm];
#pragma unroll
        for (int r = 0; r < 16; ++r) {
            int node = nw * 32 + (r & 3) + 8 * (r >> 2) + 4 * lh;
            int g = g0 + node;
            out[(size_t)g * ODIM + ow * 32 + lm] = (a2[r] + bv) * mask[g];
        }
    }
}

extern "C" void kernel_launch(void* const* d_in, const int* in_sizes, int n_in,
                              void* d_out, int out_size, void* d_ws, size_t ws_size,
                              hipStream_t stream)
{
    const float* lat  = (const float*)d_in[0];
    const float* adj  = (const float*)d_in[1];
    const float* mask = (const float*)d_in[2];
    const float* W0   = (const float*)d_in[3];
    const float* b0   = (const float*)d_in[4];
    const float* W1   = (const float*)d_in[5];
    const float* b1   = (const float*)d_in[6];
    const float* W2   = (const float*)d_in[7];
    const float* b2   = (const float*)d_in[8];
    const float* Wout = (const float*)d_in[9];
    const float* bout = (const float*)d_in[10];
    float* out = (float*)d_out;

    char* ws = (char*)d_ws;
    bf16*  msgA  = (bf16*)(ws + 0);            // 4 MiB   (frag-major msgP)
    bf16*  msgB  = (bf16*)(ws + 4194304);      // 4 MiB
    bf16*  adjP  = (bf16*)(ws + 8388608);      // 64 MiB  (frag-major bf16 adj)
    float* part  = (float*)(ws + 75497472);    // 32 MiB  (4 K-split partials)
    bf16*  WT1   = (bf16*)(ws + 109051904);    // 32 KiB
    bf16*  WT2   = (bf16*)(ws + 109084672);    // 32 KiB
    bf16*  WoutT = (bf16*)(ws + 109117440);    // 16 KiB

    prep_t0_k<<<416, 256, 0, stream>>>(lat, W0, b0, W1, W2, Wout, msgA, WT1, WT2, WoutT);

    agg_part_k<1><<<2048, 64, 0, stream>>>(adj, nullptr, adjP, msgA, part);
    combine_k<0><<<256, 256, 0, stream>>>(part, WT1, b1, msgB, nullptr, nullptr);

    agg_part_k<0><<<2048, 64, 0, stream>>>(nullptr, adjP, nullptr, msgB, part);
    combine_k<0><<<256, 256, 0, stream>>>(part, WT2, b2, msgA, nullptr, nullptr);

    agg_part_k<0><<<2048, 64, 0, stream>>>(nullptr, adjP, nullptr, msgA, part);
    combine_k<1><<<256, 256, 0, stream>>>(part, WoutT, bout, nullptr, mask, out);
}